// Round 11
// baseline (129.143 us; speedup 1.0000x reference)
//
#include <hip/hip_runtime.h>
#include <stdint.h>

// Problem constants (match reference)
#define B_ 4096
#define C_ 200
#define P_ 32
#define F_ 512
#define N_ (C_*P_)        // 6400 prototypes total
#define ALPHA_ 5.0
#define EPS_ 1e-8

typedef unsigned char u8;
typedef unsigned int u32;
typedef __attribute__((ext_vector_type(4))) float floatx4;  // MFMA C/D frag

union frag16 { int4 v; long l[2]; };   // 16 fp8 = two MFMA k-slices (virtual-K)

// ---------- prep: fp32 -> fp8 e4m3 packed + row sum-of-squares, no atomics ----------
// Packed layout: o = tm*512 + kc*64 + q*16 + r (16-B units); byte (tm*8+kc)*1024 +
// (q*16+r)*16 holds features [kc*64+q*16,+16) of row tm*16+r. One 512-thread block
// covers exactly one row-tile tm (o = blockIdx*512 + tid): writes are block-contiguous
// 8KB; the 32 per-row partials (tid === r mod 16) reduce through LDS -> direct store.
// Blocks [0,256) = A (outputs -> x2), [256,656) = B (clusters -> p2).
__global__ __launch_bounds__(512)
void prep_kernel(const float* __restrict__ outputs, const float* __restrict__ clusters,
                 u8* __restrict__ At, u8* __restrict__ Bt, float* __restrict__ sumsq,
                 u32* __restrict__ counter) {
    __shared__ float part[512];
    const int tid = threadIdx.x;
    const float* src; u8* dst; int tm, rbase;
    if (blockIdx.x < 256) { tm = blockIdx.x;       src = outputs;  dst = At; rbase = 0; }
    else                  { tm = blockIdx.x - 256; src = clusters; dst = Bt; rbase = B_; }
    const int o  = tm * 512 + tid;
    const int kc = tid >> 6, q = (tid >> 4) & 3, r = tid & 15;
    const int row = tm * 16 + r;

    const float4* s = (const float4*)(src + (size_t)row * F_ + kc * 64 + q * 16);
    float4 v0 = s[0], v1 = s[1], v2 = s[2], v3 = s[3];
    int4 w;
    w.x = __builtin_amdgcn_cvt_pk_fp8_f32(v0.x, v0.y, 0, false);
    w.x = __builtin_amdgcn_cvt_pk_fp8_f32(v0.z, v0.w, w.x, true);
    w.y = __builtin_amdgcn_cvt_pk_fp8_f32(v1.x, v1.y, 0, false);
    w.y = __builtin_amdgcn_cvt_pk_fp8_f32(v1.z, v1.w, w.y, true);
    w.z = __builtin_amdgcn_cvt_pk_fp8_f32(v2.x, v2.y, 0, false);
    w.z = __builtin_amdgcn_cvt_pk_fp8_f32(v2.z, v2.w, w.z, true);
    w.w = __builtin_amdgcn_cvt_pk_fp8_f32(v3.x, v3.y, 0, false);
    w.w = __builtin_amdgcn_cvt_pk_fp8_f32(v3.z, v3.w, w.w, true);
    *(int4*)(dst + (size_t)o * 16) = w;

    part[tid] = v0.x*v0.x + v0.y*v0.y + v0.z*v0.z + v0.w*v0.w
              + v1.x*v1.x + v1.y*v1.y + v1.z*v1.z + v1.w*v1.w
              + v2.x*v2.x + v2.y*v2.y + v2.z*v2.z + v2.w*v2.w
              + v3.x*v3.x + v3.y*v3.y + v3.z*v3.z + v3.w*v3.w;
    __syncthreads();
    if (tid < 16) {
        float acc = 0.f;
#pragma unroll
        for (int j = 0; j < 32; ++j) acc += part[tid + j * 16];
        sumsq[rbase + tm * 16 + tid] = acc;
    }
    if (blockIdx.x == 0 && tid == 0) *counter = 0;   // reset selfin's done-counter
}

// ---------- score kernel: fp8 MFMA GEMM (R8/R6 proven structure) ----------
// LDS double-buffer + global_load_lds width-16, 1-stage-ahead prefetch, one barrier/stage.
// Epilogue keeps only the per-(b,class) min VALUE (indices are algebraically redundant).
#define BM 128
#define BN 128

typedef const __attribute__((address_space(1))) unsigned int gu32_t;
typedef __attribute__((address_space(3))) unsigned int lu32_t;

__device__ __forceinline__ void gld16(const u8* g, u8* l) {
    __builtin_amdgcn_global_load_lds((gu32_t*)g, (lu32_t*)l, 16, 0, 0);
}

__global__ __launch_bounds__(256, 4)
void score_kernel(const u8* __restrict__ At, const u8* __restrict__ Bt,
                  const float* __restrict__ p2, float* __restrict__ min_d) {
    __shared__ __align__(16) u8 lds[2][16384];   // [buf][ A: 8 tiles x 1KB | B: 8 tiles x 1KB ]

    const int tid  = threadIdx.x;
    const int lane = tid & 63;
    const int w    = tid >> 6;          // wave 0..3 (2x2 wave grid, 64x64 per wave)
    const int wm   = w >> 1, wn = w & 1;
    const int bx   = blockIdx.x;        // n-tile 0..49
    const int by   = blockIdx.y;        // m-tile 0..31
    const int m0   = by * BM, n0 = bx * BN;
    const int mrow = lane & 15;
    const int quad = lane >> 4;
    const int l16  = lane * 16;

    const u8* ag = At + ((size_t)(by * 8) << 13);   // 8 row-tiles x 8KB each
    const u8* bg = Bt + ((size_t)(bx * 8) << 13);

    floatx4 zf = {0.f, 0.f, 0.f, 0.f};
    floatx4 acc[4][4];
#pragma unroll
    for (int i = 0; i < 4; ++i)
#pragma unroll
        for (int j = 0; j < 4; ++j) acc[i][j] = zf;

    // prologue: prefetch stage 0 into buf 0 (wave w loads A tiles {w,w+4}, B tiles {w,w+4})
    gld16(ag + ((w * 8) << 10) + l16,           lds[0] + w * 1024);
    gld16(ag + (((w + 4) * 8) << 10) + l16,     lds[0] + (w + 4) * 1024);
    gld16(bg + ((w * 8) << 10) + l16,           lds[0] + 8192 + w * 1024);
    gld16(bg + (((w + 4) * 8) << 10) + l16,     lds[0] + 8192 + (w + 4) * 1024);
    __syncthreads();

#pragma unroll
    for (int kc = 0; kc < 8; ++kc) {
        const int cur = kc & 1;
        if (kc < 7) {
            const int nb = cur ^ 1, kn = kc + 1;
            gld16(ag + ((w * 8 + kn) << 10) + l16,         lds[nb] + w * 1024);
            gld16(ag + (((w + 4) * 8 + kn) << 10) + l16,   lds[nb] + (w + 4) * 1024);
            gld16(bg + ((w * 8 + kn) << 10) + l16,         lds[nb] + 8192 + w * 1024);
            gld16(bg + (((w + 4) * 8 + kn) << 10) + l16,   lds[nb] + 8192 + (w + 4) * 1024);
        }
        frag16 a[4], b[4];
#pragma unroll
        for (int t = 0; t < 4; ++t) {
            a[t].v = *(const int4*)(lds[cur] + (wm * 4 + t) * 1024 + l16);
            b[t].v = *(const int4*)(lds[cur] + 8192 + (wn * 4 + t) * 1024 + l16);
        }
#pragma unroll
        for (int s = 0; s < 2; ++s)
#pragma unroll
            for (int mt = 0; mt < 4; ++mt)
#pragma unroll
                for (int nt = 0; nt < 4; ++nt)
                    acc[mt][nt] = __builtin_amdgcn_mfma_f32_16x16x32_fp8_fp8(
                        a[mt].l[s], b[nt].l[s], acc[mt][nt], 0, 0, 0);
        __syncthreads();
    }

    // Epilogue: score = p2[n] - 2*xp (x2 constant per row b — argmins unchanged).
    // C/D layout: col = lane&15, row = quad*4 + reg.
    float pg[4];
#pragma unroll
    for (int nt = 0; nt < 4; ++nt) pg[nt] = p2[n0 + wn * 64 + nt * 16 + mrow];

#pragma unroll
    for (int ch = 0; ch < 2; ++ch) {
        const int cls = bx * 4 + wn * 2 + ch;
#pragma unroll
        for (int mt = 0; mt < 4; ++mt)
#pragma unroll
            for (int reg = 0; reg < 4; ++reg) {
                float v = fminf(pg[ch * 2]     - 2.0f * acc[mt][ch * 2][reg],
                                pg[ch * 2 + 1] - 2.0f * acc[mt][ch * 2 + 1][reg]);
#pragma unroll
                for (int m = 8; m >= 1; m >>= 1) v = fminf(v, __shfl_xor(v, m));
                if (mrow == 0) {
                    int grow = m0 + wm * 64 + mt * 16 + quad * 4 + reg;
                    min_d[grow * C_ + cls] = v;
                }
            }
    }
}

// ---------- fused select + finalize (last-block-done pattern) ----------
// 64 blocks x 256 threads; each wave scans 16 samples (target value + masked min over
// wrong classes), block writes 2 partials, last finished block reduces 2x64 partials
// and writes the loss. Counter is reset by prep (stream-ordered earlier).
__global__ __launch_bounds__(256)
void selfin_kernel(const float* __restrict__ min_d, const float* __restrict__ x2,
                   const int* __restrict__ tgt,
                   float* __restrict__ part1, float* __restrict__ part2,
                   u32* __restrict__ counter, float* __restrict__ out) {
    __shared__ float p1s[4], p2s[4];
    __shared__ int last;
    const int tid = threadIdx.x, w = tid >> 6, lane = tid & 63;

    float s1 = 0.f, s2 = 0.f;
#pragma unroll
    for (int it = 0; it < 16; ++it) {
        const int b  = blockIdx.x * 64 + w * 16 + it;
        const int tc = tgt[b];
        const float* row = min_d + (size_t)b * C_;
        float vt = row[tc];          // broadcast load
        float bw = 3.4e38f;
        for (int c = lane; c < C_; c += 64) {
            float v = row[c];
            if (c != tc) bw = fminf(bw, v);
        }
#pragma unroll
        for (int m = 32; m >= 1; m >>= 1) bw = fminf(bw, __shfl_xor(bw, m));
        if (lane == 0) {
            float xx = x2[b];
            s1 += xx + vt;           // = ||x - p_target*||^2 (fp8-dot approx)
            s2 += xx + bw;           // = ||x - p_wrong*||^2
        }
    }
    if (lane == 0) { p1s[w] = s1; p2s[w] = s2; }
    __syncthreads();
    if (tid == 0) {
        part1[blockIdx.x] = p1s[0] + p1s[1] + p1s[2] + p1s[3];
        part2[blockIdx.x] = p2s[0] + p2s[1] + p2s[2] + p2s[3];
        __threadfence();
        last = (atomicAdd(counter, 1u) == 63u);
    }
    __syncthreads();
    if (last) {
        __threadfence();
        double t1 = 0.0, t2 = 0.0;
        if (tid < 64) {
            t1 = (double)((volatile const float*)part1)[tid];
            t2 = (double)((volatile const float*)part2)[tid];
        }
#pragma unroll
        for (int m = 32; m >= 1; m >>= 1) {
            t1 += __shfl_xor(t1, m);
            t2 += __shfl_xor(t2, m);
        }
        if (tid == 0) {
            double denom = (double)B_ * (double)F_;
            double tl  = t1 / denom;
            double ntl = t2 / denom;
            out[0] = (float)((1.0 - ALPHA_) * tl + ALPHA_ / (ntl + EPS_));
        }
    }
}

// ---------- launch ----------
extern "C" void kernel_launch(void* const* d_in, const int* in_sizes, int n_in,
                              void* d_out, int out_size, void* d_ws, size_t ws_size,
                              hipStream_t stream) {
    const float* outputs  = (const float*)d_in[0];
    const float* clusters = (const float*)d_in[1];
    const int*   tgt      = (const int*)d_in[2];
    float* out = (float*)d_out;

    char* ws = (char*)d_ws;
    // workspace layout (16B-aligned), total 8,693,312 bytes
    u8*     At      = (u8*)(ws);                     // packed A: 2,097,152
    u8*     Bt      = (u8*)(ws + 2097152);           // packed B: 3,276,800
    float*  sumsq   = (float*)(ws + 5373952);        // 10496*4 = 41,984 (x2 | p2)
    float*  min_d   = (float*)(ws + 5415936);        // 4096*200*4 = 3,276,800
    float*  part1   = (float*)(ws + 8692736);        // 64*4
    float*  part2   = (float*)(ws + 8692992);        // 64*4
    u32*    counter = (u32*)(ws + 8693248);          // 4
    float*  x2      = sumsq;
    float*  p2      = sumsq + B_;

    prep_kernel<<<656, 512, 0, stream>>>(outputs, clusters, At, Bt, sumsq, counter);
    score_kernel<<<dim3(N_ / BN, B_ / BM), 256, 0, stream>>>(At, Bt, p2, min_d);   // 50x32
    selfin_kernel<<<64, 256, 0, stream>>>(min_d, x2, tgt, part1, part2, counter, out);
}

// Round 12
// 122.886 us; speedup vs baseline: 1.0509x; 1.0509x over previous
//
#include <hip/hip_runtime.h>
#include <stdint.h>

// Problem constants (match reference)
#define B_ 4096
#define C_ 200
#define P_ 32
#define F_ 512
#define N_ (C_*P_)        // 6400 prototypes total
#define ALPHA_ 5.0
#define EPS_ 1e-8
#define NROWS_ (B_ + N_)  // 10496 sumsq rows (x2 then p2)

typedef unsigned char u8;
typedef __attribute__((ext_vector_type(4))) float floatx4;  // MFMA C/D frag

union frag16 { int4 v; long l[2]; };   // 16 fp8 = two MFMA k-slices (virtual-K)

__global__ void zero_kernel(float* __restrict__ sumsq) {
    int i = blockIdx.x * 256 + threadIdx.x;
    if (i < NROWS_) sumsq[i] = 0.f;
}

// ---------- prep: fp32 -> fp8 e4m3 packed + row sum-of-squares (x2 | p2) ----------
// Packed layout: o = tm*512 + kc*64 + q*16 + r (16-B units); byte (tm*8+kc)*1024 +
// (q*16+r)*16 holds features [kc*64+q*16,+16) of row tm*16+r. (R8's proven version.)
__global__ void prep_kernel(const float* __restrict__ outputs, const float* __restrict__ clusters,
                            u8* __restrict__ At, u8* __restrict__ Bt, float* __restrict__ sumsq) {
    int t = blockIdx.x * 256 + threadIdx.x;
    const float* src; u8* dst; int o, rbase;
    if (t < B_ * 32) { o = t;           src = outputs;  dst = At; rbase = 0; }
    else             { o = t - B_ * 32; src = clusters; dst = Bt; rbase = B_; }
    const int tm = o >> 9, kc = (o >> 6) & 7, q = (o >> 4) & 3, r = o & 15;
    const int row = tm * 16 + r;
    const float4* s = (const float4*)(src + (size_t)row * F_ + kc * 64 + q * 16);
    float4 v0 = s[0], v1 = s[1], v2 = s[2], v3 = s[3];
    int4 w;
    w.x = __builtin_amdgcn_cvt_pk_fp8_f32(v0.x, v0.y, 0, false);
    w.x = __builtin_amdgcn_cvt_pk_fp8_f32(v0.z, v0.w, w.x, true);
    w.y = __builtin_amdgcn_cvt_pk_fp8_f32(v1.x, v1.y, 0, false);
    w.y = __builtin_amdgcn_cvt_pk_fp8_f32(v1.z, v1.w, w.y, true);
    w.z = __builtin_amdgcn_cvt_pk_fp8_f32(v2.x, v2.y, 0, false);
    w.z = __builtin_amdgcn_cvt_pk_fp8_f32(v2.z, v2.w, w.z, true);
    w.w = __builtin_amdgcn_cvt_pk_fp8_f32(v3.x, v3.y, 0, false);
    w.w = __builtin_amdgcn_cvt_pk_fp8_f32(v3.z, v3.w, w.w, true);
    *(int4*)(dst + (size_t)o * 16) = w;

    float ss = v0.x*v0.x + v0.y*v0.y + v0.z*v0.z + v0.w*v0.w
             + v1.x*v1.x + v1.y*v1.y + v1.z*v1.z + v1.w*v1.w
             + v2.x*v2.x + v2.y*v2.y + v2.z*v2.z + v2.w*v2.w
             + v3.x*v3.x + v3.y*v3.y + v3.z*v3.z + v3.w*v3.w;
    ss += __shfl_xor(ss, 16);
    ss += __shfl_xor(ss, 32);
    if ((o & 63) < 16) atomicAdd(&sumsq[rbase + row], ss);   // 16 lanes, 16 consecutive rows
}

// ---------- score kernel: full-K LDS-resident 64x64 tile — NO K-loop barrier ----------
// K=512 is small enough that the entire A-tile (64x512 fp8 = 32KB) and B-tile (32KB)
// fit in 64KB LDS (2 blocks/CU, m132 precedent). One contiguous staging phase (each
// wave reads 16KB of the packed layout with 16 gld16s), ONE barrier, then 256 MFMAs
// with zero barriers / zero vmcnt waits. Co-resident block's staging overlaps compute.
#define TM 64
#define TN 64

typedef const __attribute__((address_space(1))) unsigned int gu32_t;
typedef __attribute__((address_space(3))) unsigned int lu32_t;

__device__ __forceinline__ void gld16(const u8* g, u8* l) {
    __builtin_amdgcn_global_load_lds((gu32_t*)g, (lu32_t*)l, 16, 0, 0);
}

__global__ __launch_bounds__(256, 2)
void score_kernel(const u8* __restrict__ At, const u8* __restrict__ Bt,
                  const float* __restrict__ p2, float* __restrict__ min_d) {
    __shared__ __align__(16) u8 ldsA[32 * 1024];   // A tile, full K: 32 chunks x 1KB
    __shared__ __align__(16) u8 ldsB[32 * 1024];   // B tile, full K

    const int tid  = threadIdx.x;
    const int lane = tid & 63;
    const int w    = tid >> 6;          // wave 0..3 (2x2 wave grid, 32x32 per wave)
    const int wm   = w >> 1, wn = w & 1;
    const int bx   = blockIdx.x;        // n-tile 0..99 (64 cols = 2 classes)
    const int by   = blockIdx.y;        // m-tile 0..63
    const int mrow = lane & 15;
    const int quad = lane >> 4;
    const int l16  = lane * 16;

    // staging: packed chunks for this block are CONTIGUOUS: A chunks [by*32, +32),
    // B chunks [bx*32, +32). Waves 0,1 stage A halves; waves 2,3 stage B halves.
    {
        const u8* g0 = (w < 2) ? (At + (((size_t)by * 32) << 10) + l16)
                               : (Bt + (((size_t)bx * 32) << 10) + l16);
        u8* l0 = (w < 2) ? ldsA : ldsB;
        const int c0 = (w & 1) * 16;
#pragma unroll
        for (int i = 0; i < 16; ++i)
            gld16(g0 + ((c0 + i) << 10), l0 + ((c0 + i) << 10));
    }
    __syncthreads();    // the ONLY barrier: drains staging once per block

    floatx4 zf = {0.f, 0.f, 0.f, 0.f};
    floatx4 acc[2][2];
#pragma unroll
    for (int i = 0; i < 2; ++i)
#pragma unroll
        for (int j = 0; j < 2; ++j) acc[i][j] = zf;

#pragma unroll
    for (int kc = 0; kc < 8; ++kc) {
        frag16 a[2], b[2];
#pragma unroll
        for (int t = 0; t < 2; ++t) {
            a[t].v = *(const int4*)(ldsA + (((wm * 2 + t) * 8 + kc) << 10) + l16);
            b[t].v = *(const int4*)(ldsB + (((wn * 2 + t) * 8 + kc) << 10) + l16);
        }
#pragma unroll
        for (int s = 0; s < 2; ++s)
#pragma unroll
            for (int mt = 0; mt < 2; ++mt)
#pragma unroll
                for (int nt = 0; nt < 2; ++nt)
                    acc[mt][nt] = __builtin_amdgcn_mfma_f32_16x16x32_fp8_fp8(
                        a[mt].l[s], b[nt].l[s], acc[mt][nt], 0, 0, 0);
    }

    // Epilogue: score = p2[n] - 2*xp (x2 constant per row b — argmins unchanged).
    // Wave covers rows [by*64+wm*32, +32) and ONE class (cls = bx*2+wn, protos 0..31).
    // C/D layout: col = lane&15, row = quad*4 + reg.
    const int cls = bx * 2 + wn;
    float pg[2];
#pragma unroll
    for (int nt = 0; nt < 2; ++nt) pg[nt] = p2[bx * 64 + wn * 32 + nt * 16 + mrow];

#pragma unroll
    for (int mt = 0; mt < 2; ++mt)
#pragma unroll
        for (int reg = 0; reg < 4; ++reg) {
            float v = fminf(pg[0] - 2.0f * acc[mt][0][reg],
                            pg[1] - 2.0f * acc[mt][1][reg]);
#pragma unroll
            for (int m = 8; m >= 1; m >>= 1) v = fminf(v, __shfl_xor(v, m));
            if (mrow == 0) {
                int grow = by * 64 + wm * 32 + mt * 16 + quad * 4 + reg;
                min_d[grow * C_ + cls] = v;
            }
        }
}

// ---------- per-sample: target value + masked min over wrong classes (values only) ----------
__global__ void select_kernel(const float* __restrict__ min_d, const float* __restrict__ x2,
                              const int* __restrict__ tgt,
                              float* __restrict__ stw, float* __restrict__ sww) {
    int b    = blockIdx.x * 4 + (threadIdx.x >> 6);
    int lane = threadIdx.x & 63;
    int tc   = tgt[b];
    const float* row = min_d + (size_t)b * C_;

    float vt = row[tc];          // broadcast load
    float bw = 3.4e38f;
    for (int c = lane; c < C_; c += 64) {
        float v = row[c];
        if (c != tc) bw = fminf(bw, v);
    }
#pragma unroll
    for (int m = 32; m >= 1; m >>= 1) bw = fminf(bw, __shfl_xor(bw, m));
    if (lane == 0) {
        float xx = x2[b];
        stw[b] = xx + vt;        // = ||x - p_target*||^2 (fp8-dot approx)
        sww[b] = xx + bw;        // = ||x - p_wrong*||^2
    }
}

// Single-block reduction of 2x4096 floats + final loss
__global__ __launch_bounds__(1024)
void finalize_kernel(const float* __restrict__ stw, const float* __restrict__ sww,
                     float* __restrict__ out) {
    __shared__ float r1[16], r2[16];
    int tid = threadIdx.x;
    float s1 = 0.f, s2 = 0.f;
#pragma unroll
    for (int i = 0; i < 4; ++i) {
        s1 += stw[tid + i * 1024];
        s2 += sww[tid + i * 1024];
    }
#pragma unroll
    for (int m = 32; m >= 1; m >>= 1) { s1 += __shfl_xor(s1, m); s2 += __shfl_xor(s2, m); }
    if ((tid & 63) == 0) { r1[tid >> 6] = s1; r2[tid >> 6] = s2; }
    __syncthreads();
    if (tid == 0) {
        double t1 = 0.0, t2 = 0.0;
#pragma unroll
        for (int i = 0; i < 16; ++i) { t1 += (double)r1[i]; t2 += (double)r2[i]; }
        double denom = (double)B_ * (double)F_;
        double tl  = t1 / denom;
        double ntl = t2 / denom;
        out[0] = (float)((1.0 - ALPHA_) * tl + ALPHA_ / (ntl + EPS_));
    }
}

// ---------- launch ----------
extern "C" void kernel_launch(void* const* d_in, const int* in_sizes, int n_in,
                              void* d_out, int out_size, void* d_ws, size_t ws_size,
                              hipStream_t stream) {
    const float* outputs  = (const float*)d_in[0];
    const float* clusters = (const float*)d_in[1];
    const int*   tgt      = (const int*)d_in[2];
    float* out = (float*)d_out;

    char* ws = (char*)d_ws;
    // workspace layout (16B-aligned), total 8,692,736 bytes
    u8*     At      = (u8*)(ws);                     // packed A: 2,097,152
    u8*     Bt      = (u8*)(ws + 2097152);           // packed B: 3,276,800
    float*  sumsq   = (float*)(ws + 5373952);        // 10496*4 = 41,984 (x2 | p2)
    float*  min_d   = (float*)(ws + 5415936);        // 4096*200*4 = 3,276,800
    float*  x2      = sumsq;
    float*  p2      = sumsq + B_;
    // per-sample partials: reuse the At region (dead after score_kernel)
    float*  stw     = (float*)(ws);                  // 4096*4
    float*  sww     = (float*)(ws + 16384);          // 4096*4

    zero_kernel<<<(NROWS_ + 255) / 256, 256, 0, stream>>>(sumsq);                           // 41 blocks
    prep_kernel<<<(B_ * 32 + N_ * 32) / 256, 256, 0, stream>>>(outputs, clusters, At, Bt, sumsq); // 1312
    score_kernel<<<dim3(N_ / TN, B_ / TM), 256, 0, stream>>>(At, Bt, p2, min_d);            // 100x64
    select_kernel<<<B_ / 4, 256, 0, stream>>>(min_d, x2, tgt, stw, sww);                    // 1024
    finalize_kernel<<<1, 1024, 0, stream>>>(stw, sww, out);
}